// Round 6
// baseline (464.796 us; speedup 1.0000x reference)
//
#include <hip/hip_runtime.h>
#include <hip/hip_bf16.h>
#include <math.h>

// MOE: out[b,o] = sum_n gelu(x@gw^T+gb)[b,n] * (x @ W_n^T)[b,o]
// R6: pre-scale activations xs[n][b][i] = bf16(g[b,n]*x[b,i]) -> ONE pure
// bf16 GEMM (M=4096,N=1024,K=32768), single accumulator, m201 geometry:
// BM=BN=256, 8 waves (2Mx4N) of 128x64, BK=64, 4 phases/kt (16 MFMA each),
// double-buffered LDS (128 KiB), distance-1 prefetch spread 3/3/2/0 over
// phases, vmcnt(0)+barrier once per kt, setprio on MFMA clusters.
// Split-K x4 via fp32 atomics. Workspace-laddered rounds (1/4/8) by ws_size.

#define BSZ  4096
#define NEXP 32
#define IDIM 1024
#define ODIM 1024

typedef unsigned short u16;
typedef __attribute__((ext_vector_type(8))) short bf16x8;
typedef __attribute__((ext_vector_type(4))) float f32x4;

#define GLOAD_LDS16(g, l) __builtin_amdgcn_global_load_lds( \
    (const __attribute__((address_space(1))) void*)(g),     \
    (__attribute__((address_space(3))) void*)(l), 16, 0, 0)

#define SBAR __builtin_amdgcn_sched_barrier(0)
#define WAITV0 asm volatile("s_waitcnt vmcnt(0)" ::: "memory")
#define WAITL0 do { asm volatile("s_waitcnt lgkmcnt(0)" ::: "memory"); SBAR; } while (0)
#define BARRIER do { __builtin_amdgcn_s_barrier(); SBAR; } while (0)

__device__ __forceinline__ u16 f2bf(float f) {
  unsigned u = __float_as_uint(f);
  return (u16)((u + 0x7FFFu + ((u >> 16) & 1u)) >> 16);  // RNE
}

// ---------------- zero d_out ----------------
__global__ void zero_kernel(float* __restrict__ out) {
  int i = blockIdx.x * blockDim.x + threadIdx.x;
  ((float4*)out)[i] = make_float4(0.f, 0.f, 0.f, 0.f);
}

// ---------------- fp32 -> bf16 conversion (8 elems/thread) ----------------
__global__ void conv_kernel(const float* __restrict__ in, u16* __restrict__ outb) {
  int i = blockIdx.x * blockDim.x + threadIdx.x;
  const float4* p = (const float4*)in + (size_t)i * 2;
  float4 a = p[0], b = p[1];
  union { bf16x8 v; u16 s[8]; } o;
  o.s[0] = f2bf(a.x); o.s[1] = f2bf(a.y); o.s[2] = f2bf(a.z); o.s[3] = f2bf(a.w);
  o.s[4] = f2bf(b.x); o.s[5] = f2bf(b.y); o.s[6] = f2bf(b.z); o.s[7] = f2bf(b.w);
  ((bf16x8*)outb)[i] = o.v;
}

// ---------------- gate: gT[n][b] = gelu(x[b]·gw[n] + gb[n]) ----------------
__global__ void gate_kernel(const float* __restrict__ x, const float* __restrict__ gw,
                            const float* __restrict__ gb, float* __restrict__ gT) {
  const int lane = threadIdx.x & 63;
  const int row = blockIdx.x * 4 + (threadIdx.x >> 6);
  const float4* xr = (const float4*)(x + (size_t)row * IDIM);
  float4 xv[4];
#pragma unroll
  for (int t = 0; t < 4; ++t) xv[t] = xr[t * 64 + lane];
  for (int n = 0; n < NEXP; ++n) {
    const float4* wr = (const float4*)(gw + (size_t)n * IDIM);
    float s = 0.f;
#pragma unroll
    for (int t = 0; t < 4; ++t) {
      float4 wv = wr[t * 64 + lane];
      s += xv[t].x * wv.x + xv[t].y * wv.y + xv[t].z * wv.z + xv[t].w * wv.w;
    }
#pragma unroll
    for (int off = 32; off > 0; off >>= 1) s += __shfl_down(s, off, 64);
    if (lane == 0) {
      float v = s + gb[n];
      gT[(size_t)n * BSZ + row] = 0.5f * v * (1.0f + erff(v * 0.70710678118f));
    }
  }
}

// ---------------- xs[e][b][i] = bf16(g[b, base+e] * x[b][i]) ----------------
__global__ void scale_kernel(const float* __restrict__ x, const float* __restrict__ gT,
                             u16* __restrict__ xs, int base) {
  int idx = blockIdx.x * 256 + threadIdx.x;
  int chunk = idx & 127;                 // 8-elem chunk within row
  int b = (idx >> 7) & 4095;
  int e = idx >> 19;
  const float4* xp = (const float4*)(x + ((size_t)b << 10) + chunk * 8);
  float4 v0 = xp[0], v1 = xp[1];
  float g = gT[((size_t)(base + e) << 12) + b];
  union { bf16x8 v; u16 s[8]; } o;
  o.s[0] = f2bf(g * v0.x); o.s[1] = f2bf(g * v0.y);
  o.s[2] = f2bf(g * v0.z); o.s[3] = f2bf(g * v0.w);
  o.s[4] = f2bf(g * v1.x); o.s[5] = f2bf(g * v1.y);
  o.s[6] = f2bf(g * v1.z); o.s[7] = f2bf(g * v1.w);
  *(bf16x8*)&xs[((size_t)e << 22) + ((size_t)b << 10) + chunk * 8] = o.v;
}

// ---------------- main GEMM ----------------
// 256 blocks, 512 threads (8 waves: 2M x 4N, wave = 128x64).
// grid task: (mtile 0..15) x (ntile 0..3) x (split 0..3); K = eps experts.
__global__ __launch_bounds__(512, 2) void gemm_kernel(
    const u16* __restrict__ xs,   // [EPR][4096][1024] bf16 (pre-scaled)
    const u16* __restrict__ wb,   // [EPR][1024][1024] bf16 (e,o,i)
    float* __restrict__ out,      // [4096][1024] fp32
    int eps)                      // experts per split (EPR/4)
{
  __shared__ u16 As[2][256 * 64];   // 64 KB
  __shared__ u16 Bs[2][256 * 64];   // 64 KB  (128 KiB total)

  const int tid  = threadIdx.x;
  const int lane = tid & 63;
  const int wid  = tid >> 6;     // 0..7
  const int wm   = wid >> 2;     // 0..1 (M)
  const int wn   = wid & 3;      // 0..3 (N)

  // XCD-chunked block swizzle (256 % 8 == 0 -> bijective); 16 blocks/grp share W panel
  const int orig  = blockIdx.x;
  const int wgid  = (orig & 7) * 32 + (orig >> 3);
  const int mtile = wgid & 15;
  const int grp   = wgid >> 4;          // 0..15
  const int split = grp & 3;
  const int col0  = (grp >> 2) * 256;
  const int row0  = mtile * 256;

  // staging: lane -> (row-in-chunk, pre-swizzled source granule)
  const int srow = lane >> 3;
  const int jsrc = (lane & 7) ^ srow;
  size_t a_off[4], b_off[4];
#pragma unroll
  for (int l = 0; l < 4; ++l) {
    a_off[l] = ((size_t)(row0 + (wid * 4 + l) * 8 + srow) << 10) + jsrc * 8;
    b_off[l] = ((size_t)(col0 + (wid * 4 + l) * 8 + srow) << 10) + jsrc * 8;
  }

  const int frow = lane & 15;
  const int hi   = lane >> 4;
  const int g0 = hi ^ (frow & 7);        // granule, kk=0
  const int g1 = (4 + hi) ^ (frow & 7);  // granule, kk=1
  const int arow = (wm * 128 + frow) * 64;
  const int brow = (wn * 64 + frow) * 64;

  f32x4 acc[8][4];
#pragma unroll
  for (int i = 0; i < 8; ++i)
#pragma unroll
    for (int j = 0; j < 4; ++j) acc[i][j] = f32x4{0.f, 0.f, 0.f, 0.f};

  auto SA = [&](int buf, int kt, int l) {
    const int e = split * eps + (kt >> 4);
    const size_t i0 = (size_t)((kt & 15) << 6);
    GLOAD_LDS16(xs + ((size_t)e << 22) + a_off[l] + i0, &As[buf][(wid * 4 + l) * 512]);
  };
  auto SB = [&](int buf, int kt, int l) {
    const int e = split * eps + (kt >> 4);
    const size_t i0 = (size_t)((kt & 15) << 6);
    GLOAD_LDS16(wb + ((size_t)e << 20) + b_off[l] + i0, &Bs[buf][(wid * 4 + l) * 512]);
  };

  const int NKT = eps << 4;

  // prologue: stage tile 0, drain, rendezvous
#pragma unroll
  for (int l = 0; l < 4; ++l) { SA(0, 0, l); SB(0, 0, l); }
  WAITV0;
  BARRIER;

  int cur = 0;
#pragma unroll 1
  for (int kt = 0; kt < NKT; ++kt) {
    const u16* A_ = &As[cur][0];
    const u16* B_ = &Bs[cur][0];
    const int nb = cur ^ 1;
    const bool pf = (kt + 1 < NKT);

    // ---- P0: B[kk0] + A[kk0, mi0-3]; stage A0,A1,B0 ----
    bf16x8 bA[4], a0[4];
#pragma unroll
    for (int ni = 0; ni < 4; ++ni) bA[ni] = *(const bf16x8*)&B_[brow + ni * 1024 + g0 * 8];
#pragma unroll
    for (int mi = 0; mi < 4; ++mi) a0[mi] = *(const bf16x8*)&A_[arow + mi * 1024 + g0 * 8];
    if (pf) { SA(nb, kt + 1, 0); SA(nb, kt + 1, 1); SB(nb, kt + 1, 0); }
    BARRIER; WAITL0;
    __builtin_amdgcn_s_setprio(1);
#pragma unroll
    for (int mi = 0; mi < 4; ++mi)
#pragma unroll
      for (int ni = 0; ni < 4; ++ni)
        acc[mi][ni] = __builtin_amdgcn_mfma_f32_16x16x32_bf16(a0[mi], bA[ni], acc[mi][ni], 0, 0, 0);
    __builtin_amdgcn_s_setprio(0);
    BARRIER;

    // ---- P1: A[kk0, mi4-7]; stage A2,A3,B1 ----
    bf16x8 a1[4];
#pragma unroll
    for (int mi = 0; mi < 4; ++mi) a1[mi] = *(const bf16x8*)&A_[arow + (mi + 4) * 1024 + g0 * 8];
    if (pf) { SA(nb, kt + 1, 2); SA(nb, kt + 1, 3); SB(nb, kt + 1, 1); }
    BARRIER; WAITL0;
    __builtin_amdgcn_s_setprio(1);
#pragma unroll
    for (int mi = 0; mi < 4; ++mi)
#pragma unroll
      for (int ni = 0; ni < 4; ++ni)
        acc[mi + 4][ni] = __builtin_amdgcn_mfma_f32_16x16x32_bf16(a1[mi], bA[ni], acc[mi + 4][ni], 0, 0, 0);
    __builtin_amdgcn_s_setprio(0);
    BARRIER;

    // ---- P2: B[kk1] + A[kk1, mi0-3]; stage B2,B3 ----
    bf16x8 bB[4], a2[4];
#pragma unroll
    for (int ni = 0; ni < 4; ++ni) bB[ni] = *(const bf16x8*)&B_[brow + ni * 1024 + g1 * 8];
#pragma unroll
    for (int mi = 0; mi < 4; ++mi) a2[mi] = *(const bf16x8*)&A_[arow + mi * 1024 + g1 * 8];
    if (pf) { SB(nb, kt + 1, 2); SB(nb, kt + 1, 3); }
    BARRIER; WAITL0;
    __builtin_amdgcn_s_setprio(1);
#pragma unroll
    for (int mi = 0; mi < 4; ++mi)
#pragma unroll
      for (int ni = 0; ni < 4; ++ni)
        acc[mi][ni] = __builtin_amdgcn_mfma_f32_16x16x32_bf16(a2[mi], bB[ni], acc[mi][ni], 0, 0, 0);
    __builtin_amdgcn_s_setprio(0);
    BARRIER;

    // ---- P3: A[kk1, mi4-7]; no stage; tile-boundary wait ----
    bf16x8 a3[4];
#pragma unroll
    for (int mi = 0; mi < 4; ++mi) a3[mi] = *(const bf16x8*)&A_[arow + (mi + 4) * 1024 + g1 * 8];
    BARRIER; WAITL0;
    __builtin_amdgcn_s_setprio(1);
#pragma unroll
    for (int mi = 0; mi < 4; ++mi)
#pragma unroll
      for (int ni = 0; ni < 4; ++ni)
        acc[mi + 4][ni] = __builtin_amdgcn_mfma_f32_16x16x32_bf16(a3[mi], bB[ni], acc[mi + 4][ni], 0, 0, 0);
    __builtin_amdgcn_s_setprio(0);
    if (pf) WAITV0;    // tile kt+1 fully resident (last stage issued in P2)
    BARRIER;           // rendezvous: all waves' kt reads done, kt+1 visible
    cur ^= 1;
  }

  // split-K contribution via atomics (out pre-zeroed)
  const int orow0 = row0 + wm * 128 + hi * 4;
  const int ocol0 = col0 + wn * 64 + frow;
#pragma unroll
  for (int mi = 0; mi < 8; ++mi)
#pragma unroll
    for (int j = 0; j < 4; ++j) {
      const int r = orow0 + mi * 16 + j;
#pragma unroll
      for (int ni = 0; ni < 4; ++ni)
        atomicAdd(out + (size_t)r * ODIM + ocol0 + ni * 16, acc[mi][ni][j]);
    }
}

extern "C" void kernel_launch(void* const* d_in, const int* in_sizes, int n_in,
                              void* d_out, int out_size, void* d_ws, size_t ws_size,
                              hipStream_t stream) {
  const float* x  = (const float*)d_in[0];   // [4096][1024]
  const float* w  = (const float*)d_in[1];   // [32][1024][1024]
  const float* gw = (const float*)d_in[2];   // [32][1024]
  const float* gb = (const float*)d_in[3];   // [32]
  float* out = (float*)d_out;                // [4096][1024]

  const size_t MiB = 1u << 20;
  // experts per round, laddered by workspace size (deterministic per session)
  int EPR;
  if      (ws_size >= 321 * MiB) EPR = 32;
  else if (ws_size >=  81 * MiB) EPR = 8;
  else                           EPR = 4;
  const int NR = NEXP / EPR;

  u16*   xs   = (u16*)d_ws;                                    // EPR * 8 MiB
  u16*   wbuf = (u16*)((char*)d_ws + (size_t)EPR * 8 * MiB);   // EPR * 2 MiB
  float* gT   = (float*)((char*)d_ws + (size_t)EPR * 10 * MiB);// 512 KiB

  zero_kernel<<<(BSZ * ODIM / 4) / 256, 256, 0, stream>>>(out);
  gate_kernel<<<BSZ / 4, 256, 0, stream>>>(x, gw, gb, gT);

  for (int r = 0; r < NR; ++r) {
    conv_kernel<<<EPR * 512, 256, 0, stream>>>(w + (size_t)r * EPR * IDIM * ODIM, wbuf);
    scale_kernel<<<EPR * 2048, 256, 0, stream>>>(x, gT, xs, r * EPR);
    gemm_kernel<<<256, 512, 0, stream>>>(xs, wbuf, out, EPR / 4);
  }
}

// Round 7
// 450.503 us; speedup vs baseline: 1.0317x; 1.0317x over previous
//
#include <hip/hip_runtime.h>
#include <hip/hip_bf16.h>
#include <math.h>

// MOE: out[b,o] = sum_n gelu(x@gw^T+gb)[b,n] * (x @ W_n^T)[b,o]
// R7: xs pre-scale -> pure bf16 GEMM (M=4096,N=1024,K=32768), single acc.
// m201 geometry: BM=BN=256, BK=64, 8 waves (2Mx4N), wave 128x64 with phase-
// banded rows. 4 phases/kt x 16 MFMA; half-tile staging 4/2/2/0 loads over
// phases into the freed opposite buffer; counted vmcnt(6)@P1 / vmcnt(2)@P3
// (never 0 in steady state). Split-K x4 atomics.

#define BSZ  4096
#define NEXP 32
#define IDIM 1024
#define ODIM 1024

typedef unsigned short u16;
typedef __attribute__((ext_vector_type(8))) short bf16x8;
typedef __attribute__((ext_vector_type(4))) float f32x4;

#define GLOAD_LDS16(g, l) __builtin_amdgcn_global_load_lds( \
    (const __attribute__((address_space(1))) void*)(g),     \
    (__attribute__((address_space(3))) void*)(l), 16, 0, 0)

#define SBAR __builtin_amdgcn_sched_barrier(0)
#define WAITV6 do { asm volatile("s_waitcnt vmcnt(6)" ::: "memory"); SBAR; } while (0)
#define WAITV2 do { asm volatile("s_waitcnt vmcnt(2)" ::: "memory"); SBAR; } while (0)
#define WAITV0 do { asm volatile("s_waitcnt vmcnt(0)" ::: "memory"); SBAR; } while (0)
#define WAITL0 do { asm volatile("s_waitcnt lgkmcnt(0)" ::: "memory"); SBAR; } while (0)
#define BARRIER do { __builtin_amdgcn_s_barrier(); SBAR; } while (0)

__device__ __forceinline__ u16 f2bf(float f) {
  unsigned u = __float_as_uint(f);
  return (u16)((u + 0x7FFFu + ((u >> 16) & 1u)) >> 16);  // RNE
}

// ---------------- zero d_out ----------------
__global__ void zero_kernel(float* __restrict__ out) {
  int i = blockIdx.x * blockDim.x + threadIdx.x;
  ((float4*)out)[i] = make_float4(0.f, 0.f, 0.f, 0.f);
}

// ---------------- fp32 -> bf16 conversion (8 elems/thread) ----------------
__global__ void conv_kernel(const float* __restrict__ in, u16* __restrict__ outb) {
  int i = blockIdx.x * blockDim.x + threadIdx.x;
  const float4* p = (const float4*)in + (size_t)i * 2;
  float4 a = p[0], b = p[1];
  union { bf16x8 v; u16 s[8]; } o;
  o.s[0] = f2bf(a.x); o.s[1] = f2bf(a.y); o.s[2] = f2bf(a.z); o.s[3] = f2bf(a.w);
  o.s[4] = f2bf(b.x); o.s[5] = f2bf(b.y); o.s[6] = f2bf(b.z); o.s[7] = f2bf(b.w);
  ((bf16x8*)outb)[i] = o.v;
}

// ---------------- gate: gT[n][b] = gelu(x[b]·gw[n] + gb[n]) ----------------
__global__ void gate_kernel(const float* __restrict__ x, const float* __restrict__ gw,
                            const float* __restrict__ gb, float* __restrict__ gT) {
  const int lane = threadIdx.x & 63;
  const int row = blockIdx.x * 4 + (threadIdx.x >> 6);
  const float4* xr = (const float4*)(x + (size_t)row * IDIM);
  float4 xv[4];
#pragma unroll
  for (int t = 0; t < 4; ++t) xv[t] = xr[t * 64 + lane];
  for (int n = 0; n < NEXP; ++n) {
    const float4* wr = (const float4*)(gw + (size_t)n * IDIM);
    float s = 0.f;
#pragma unroll
    for (int t = 0; t < 4; ++t) {
      float4 wv = wr[t * 64 + lane];
      s += xv[t].x * wv.x + xv[t].y * wv.y + xv[t].z * wv.z + xv[t].w * wv.w;
    }
#pragma unroll
    for (int off = 32; off > 0; off >>= 1) s += __shfl_down(s, off, 64);
    if (lane == 0) {
      float v = s + gb[n];
      gT[(size_t)n * BSZ + row] = 0.5f * v * (1.0f + erff(v * 0.70710678118f));
    }
  }
}

// ---------------- xs[e][b][i] = bf16(g[b, base+e] * x[b][i]) ----------------
__global__ void scale_kernel(const float* __restrict__ x, const float* __restrict__ gT,
                             u16* __restrict__ xs, int base) {
  int idx = blockIdx.x * 256 + threadIdx.x;
  int chunk = idx & 127;
  int b = (idx >> 7) & 4095;
  int e = idx >> 19;
  const float4* xp = (const float4*)(x + ((size_t)b << 10) + chunk * 8);
  float4 v0 = xp[0], v1 = xp[1];
  float g = gT[((size_t)(base + e) << 12) + b];
  union { bf16x8 v; u16 s[8]; } o;
  o.s[0] = f2bf(g * v0.x); o.s[1] = f2bf(g * v0.y);
  o.s[2] = f2bf(g * v0.z); o.s[3] = f2bf(g * v0.w);
  o.s[4] = f2bf(g * v1.x); o.s[5] = f2bf(g * v1.y);
  o.s[6] = f2bf(g * v1.z); o.s[7] = f2bf(g * v1.w);
  *(bf16x8*)&xs[((size_t)e << 22) + ((size_t)b << 10) + chunk * 8] = o.v;
}

// ---------------- main GEMM ----------------
// 256 blocks, 512 threads (8 waves 2Mx4N). Block tile 256x256, BK=64.
// Phase p computes block-rows [p*64, p*64+64): wave (wm,wn) rows p*64+wm*32..+32,
// cols wn*64..+64. A-half0 = rows 0-127 (consumed after P1); A-half1 after P3;
// B consumed at P0 (held in regs).
__global__ __launch_bounds__(512, 2) void gemm_kernel(
    const u16* __restrict__ xs,   // [EPR][4096][1024] bf16 (pre-scaled)
    const u16* __restrict__ wb,   // [EPR][1024][1024] bf16 (e,o,i)
    float* __restrict__ out,      // [4096][1024] fp32
    int eps)                      // experts per split (EPR/4)
{
  __shared__ u16 As[2][256 * 64];   // 64 KB
  __shared__ u16 Bs[2][256 * 64];   // 64 KB (128 KiB total)

  const int tid  = threadIdx.x;
  const int lane = tid & 63;
  const int wid  = tid >> 6;     // 0..7
  const int wm   = wid >> 2;     // 0..1
  const int wn   = wid & 3;      // 0..3

  // XCD-chunked block swizzle (256 % 8 == 0 -> bijective)
  const int orig  = blockIdx.x;
  const int wgid  = (orig & 7) * 32 + (orig >> 3);
  const int mtile = wgid & 15;          // 16 blocks/grp share the W panel
  const int grp   = wgid >> 4;          // 0..15 = (ntile, split)
  const int split = grp & 3;
  const int col0  = (grp >> 2) * 256;
  const int row0  = mtile * 256;

  const int srow = lane >> 3;
  const int jsrc = (lane & 7) ^ srow;   // pre-swizzled source granule
  const size_t a_base = (size_t)(row0 + wid * 8 + srow) * 1024 + jsrc * 8;
  const size_t b_base = (size_t)(col0 + wid * 8 + srow) * 1024 + jsrc * 8;

  const int frow = lane & 15;
  const int hi   = lane >> 4;
  const int fs   = frow & 7;

  f32x4 acc[4][2][4];
#pragma unroll
  for (int p = 0; p < 4; ++p)
#pragma unroll
    for (int ri = 0; ri < 2; ++ri)
#pragma unroll
      for (int ni = 0; ni < 4; ++ni) acc[p][ri][ni] = f32x4{0.f, 0.f, 0.f, 0.f};

  // stage one half-unit (h=0/1) load l (0/1): 8KB per call per block
  auto SA = [&](int buf, int kt, int h, int l) {
    const int e = split * eps + (kt >> 4);
    const size_t off = a_base + (size_t)(h * 128 + l * 64) * 1024 + ((kt & 15) << 6);
    GLOAD_LDS16(xs + ((size_t)e << 22) + off, &As[buf][(h * 128 + l * 64 + wid * 8) * 64]);
  };
  auto SB = [&](int buf, int kt, int h, int l) {
    const int e = split * eps + (kt >> 4);
    const size_t off = b_base + (size_t)(h * 128 + l * 64) * 1024 + ((kt & 15) << 6);
    GLOAD_LDS16(wb + ((size_t)e << 20) + off, &Bs[buf][(h * 128 + l * 64 + wid * 8) * 64]);
  };

  const int NKT = eps << 4;

  // prologue: stage tile 0 fully, drain (once), rendezvous
  SA(0, 0, 0, 0); SA(0, 0, 0, 1); SA(0, 0, 1, 0); SA(0, 0, 1, 1);
  SB(0, 0, 0, 0); SB(0, 0, 0, 1); SB(0, 0, 1, 0); SB(0, 0, 1, 1);
  WAITV0;
  BARRIER;

  int cur = 0;
#pragma unroll 1
  for (int kt = 0; kt < NKT; ++kt) {
    const u16* A_ = &As[cur][0];
    const u16* B_ = &Bs[cur][0];
    const int nb = cur ^ 1;
    const bool pf = (kt + 1 < NKT);

    bf16x8 breg[4][2];

    // ======== P0: read all B (8) + A band0 (4); stage kt+1 B0',B1' ========
#pragma unroll
    for (int ni = 0; ni < 4; ++ni)
#pragma unroll
      for (int kk = 0; kk < 2; ++kk)
        breg[ni][kk] = *(const bf16x8*)&B_[(wn * 64 + ni * 16 + frow) * 64 + (((kk << 2) + hi) ^ fs) * 8];
    {
      bf16x8 a_[2][2];
#pragma unroll
      for (int ri = 0; ri < 2; ++ri)
#pragma unroll
        for (int kk = 0; kk < 2; ++kk)
          a_[ri][kk] = *(const bf16x8*)&A_[(wm * 32 + ri * 16 + frow) * 64 + (((kk << 2) + hi) ^ fs) * 8];
      if (pf) { SB(nb, kt + 1, 0, 0); SB(nb, kt + 1, 0, 1); SB(nb, kt + 1, 1, 0); SB(nb, kt + 1, 1, 1); }
      BARRIER;
      WAITL0;
      __builtin_amdgcn_s_setprio(1);
#pragma unroll
      for (int ri = 0; ri < 2; ++ri)
#pragma unroll
        for (int ni = 0; ni < 4; ++ni)
#pragma unroll
          for (int kk = 0; kk < 2; ++kk)
            acc[0][ri][ni] = __builtin_amdgcn_mfma_f32_16x16x32_bf16(
                a_[ri][kk], breg[ni][kk], acc[0][ri][ni], 0, 0, 0);
      __builtin_amdgcn_s_setprio(0);
      BARRIER;
    }

    // ======== P1: A band1 (4); stage kt+1 A0'; vmcnt(6) proves this kt's A-half1 ========
    {
      bf16x8 a_[2][2];
#pragma unroll
      for (int ri = 0; ri < 2; ++ri)
#pragma unroll
        for (int kk = 0; kk < 2; ++kk)
          a_[ri][kk] = *(const bf16x8*)&A_[(64 + wm * 32 + ri * 16 + frow) * 64 + (((kk << 2) + hi) ^ fs) * 8];
      if (pf) { SA(nb, kt + 1, 0, 0); SA(nb, kt + 1, 0, 1); }
      BARRIER;
      WAITL0;
      __builtin_amdgcn_s_setprio(1);
#pragma unroll
      for (int ri = 0; ri < 2; ++ri)
#pragma unroll
        for (int ni = 0; ni < 4; ++ni)
#pragma unroll
          for (int kk = 0; kk < 2; ++kk)
            acc[1][ri][ni] = __builtin_amdgcn_mfma_f32_16x16x32_bf16(
                a_[ri][kk], breg[ni][kk], acc[1][ri][ni], 0, 0, 0);
      __builtin_amdgcn_s_setprio(0);
      if (pf) { WAITV6; } else { WAITV0; }
      BARRIER;
    }

    // ======== P2: A band2 (4); stage kt+1 A1' ========
    {
      bf16x8 a_[2][2];
#pragma unroll
      for (int ri = 0; ri < 2; ++ri)
#pragma unroll
        for (int kk = 0; kk < 2; ++kk)
          a_[ri][kk] = *(const bf16x8*)&A_[(128 + wm * 32 + ri * 16 + frow) * 64 + (((kk << 2) + hi) ^ fs) * 8];
      if (pf) { SA(nb, kt + 1, 1, 0); SA(nb, kt + 1, 1, 1); }
      BARRIER;
      WAITL0;
      __builtin_amdgcn_s_setprio(1);
#pragma unroll
      for (int ri = 0; ri < 2; ++ri)
#pragma unroll
        for (int ni = 0; ni < 4; ++ni)
#pragma unroll
          for (int kk = 0; kk < 2; ++kk)
            acc[2][ri][ni] = __builtin_amdgcn_mfma_f32_16x16x32_bf16(
                a_[ri][kk], breg[ni][kk], acc[2][ri][ni], 0, 0, 0);
      __builtin_amdgcn_s_setprio(0);
      BARRIER;
    }

    // ======== P3: A band3 (4); no stage; vmcnt(2) proves kt+1 B+A0 ========
    {
      bf16x8 a_[2][2];
#pragma unroll
      for (int ri = 0; ri < 2; ++ri)
#pragma unroll
        for (int kk = 0; kk < 2; ++kk)
          a_[ri][kk] = *(const bf16x8*)&A_[(192 + wm * 32 + ri * 16 + frow) * 64 + (((kk << 2) + hi) ^ fs) * 8];
      BARRIER;
      WAITL0;
      __builtin_amdgcn_s_setprio(1);
#pragma unroll
      for (int ri = 0; ri < 2; ++ri)
#pragma unroll
        for (int ni = 0; ni < 4; ++ni)
#pragma unroll
          for (int kk = 0; kk < 2; ++kk)
            acc[3][ri][ni] = __builtin_amdgcn_mfma_f32_16x16x32_bf16(
                a_[ri][kk], breg[ni][kk], acc[3][ri][ni], 0, 0, 0);
      __builtin_amdgcn_s_setprio(0);
      if (pf) { WAITV2; }
      BARRIER;
    }
    cur ^= 1;
  }

  // split-K contribution via atomics (out pre-zeroed)
#pragma unroll
  for (int p = 0; p < 4; ++p)
#pragma unroll
    for (int ri = 0; ri < 2; ++ri)
#pragma unroll
      for (int j = 0; j < 4; ++j) {
        const int r = row0 + p * 64 + wm * 32 + ri * 16 + hi * 4 + j;
#pragma unroll
        for (int ni = 0; ni < 4; ++ni)
          atomicAdd(out + (size_t)r * ODIM + col0 + wn * 64 + ni * 16 + frow,
                    acc[p][ri][ni][j]);
      }
}

extern "C" void kernel_launch(void* const* d_in, const int* in_sizes, int n_in,
                              void* d_out, int out_size, void* d_ws, size_t ws_size,
                              hipStream_t stream) {
  const float* x  = (const float*)d_in[0];   // [4096][1024]
  const float* w  = (const float*)d_in[1];   // [32][1024][1024]
  const float* gw = (const float*)d_in[2];   // [32][1024]
  const float* gb = (const float*)d_in[3];   // [32]
  float* out = (float*)d_out;                // [4096][1024]

  const size_t MiB = 1u << 20;
  int EPR;
  if      (ws_size >= 321 * MiB) EPR = 32;
  else if (ws_size >=  81 * MiB) EPR = 8;
  else                           EPR = 4;
  const int NR = NEXP / EPR;

  u16*   xs   = (u16*)d_ws;                                     // EPR * 8 MiB
  u16*   wbuf = (u16*)((char*)d_ws + (size_t)EPR * 8 * MiB);    // EPR * 2 MiB
  float* gT   = (float*)((char*)d_ws + (size_t)EPR * 10 * MiB); // 512 KiB

  zero_kernel<<<(BSZ * ODIM / 4) / 256, 256, 0, stream>>>(out);
  gate_kernel<<<BSZ / 4, 256, 0, stream>>>(x, gw, gb, gT);

  for (int r = 0; r < NR; ++r) {
    conv_kernel<<<EPR * 512, 256, 0, stream>>>(w + (size_t)r * EPR * IDIM * ODIM, wbuf);
    scale_kernel<<<EPR * 2048, 256, 0, stream>>>(x, gT, xs, r * EPR);
    gemm_kernel<<<256, 512, 0, stream>>>(xs, wbuf, out, EPR / 4);
  }
}